// Round 2
// baseline (137.374 us; speedup 1.0000x reference)
//
#include <hip/hip_runtime.h>
#include <stdint.h>

#define NR 16384
#define KI 256
#define MO 128
#define ALPHA 0.01f
#define CH 32            // rows per chunk
#define NCH (NR / CH)    // 512 chunks
#define SUP 16           // chunks per super
#define NS (NCH / SUP)   // 32 supers

typedef unsigned long long u64;

// sortable key: monotone float order, index tie-break (rank is a bijection)
static __device__ __forceinline__ u64 sort_key(float f, int j) {
    unsigned u = __float_as_uint(f);
    u ^= ((unsigned)((int)u >> 31)) | 0x80000000u;
    return (((u64)u) << 14) | (unsigned)(j & 0x3FFF);
}

// ---------------- K1: h = x@W^T (64x128 tile) + fused s1,s2,keys ----------------
__global__ __launch_bounds__(256) void k_gemm_fused(const float* __restrict__ x,
                                                    const float* __restrict__ w,
                                                    const float* __restrict__ a1,
                                                    const float* __restrict__ a2,
                                                    float* __restrict__ h,
                                                    float* __restrict__ s1,
                                                    float* __restrict__ s2,
                                                    u64* __restrict__ keys) {
    __shared__ float As[16][68];    // [k][row]
    __shared__ float Bs[16][132];   // [k][col]
    const int t = threadIdx.x;
    const int rowBase = blockIdx.x * 64;
    const int tx = t & 15;          // col group: cols tx*8..tx*8+7
    const int ty = t >> 4;          // row group: rows ty*4..ty*4+3
    const int ar = t >> 2, ak = (t & 3) << 2;   // A staging: row ar, k ak..ak+3
    const int br = t >> 1, bk = (t & 1) << 3;   // B staging: col br, k bk..bk+7
    float acc[4][8] = {};
    for (int k0 = 0; k0 < KI; k0 += 16) {
        float4 av  = *(const float4*)&x[(rowBase + ar) * KI + k0 + ak];
        float4 bv0 = *(const float4*)&w[br * KI + k0 + bk];
        float4 bv1 = *(const float4*)&w[br * KI + k0 + bk + 4];
        __syncthreads();
        As[ak + 0][ar] = av.x; As[ak + 1][ar] = av.y;
        As[ak + 2][ar] = av.z; As[ak + 3][ar] = av.w;
        Bs[bk + 0][br] = bv0.x; Bs[bk + 1][br] = bv0.y;
        Bs[bk + 2][br] = bv0.z; Bs[bk + 3][br] = bv0.w;
        Bs[bk + 4][br] = bv1.x; Bs[bk + 5][br] = bv1.y;
        Bs[bk + 6][br] = bv1.z; Bs[bk + 7][br] = bv1.w;
        __syncthreads();
#pragma unroll
        for (int k = 0; k < 16; ++k) {
            float4 a4 = *(const float4*)&As[k][ty << 2];
            float4 b0 = *(const float4*)&Bs[k][tx << 3];
            float4 b1 = *(const float4*)&Bs[k][(tx << 3) + 4];
            float a[4] = {a4.x, a4.y, a4.z, a4.w};
            float b[8] = {b0.x, b0.y, b0.z, b0.w, b1.x, b1.y, b1.z, b1.w};
#pragma unroll
            for (int i = 0; i < 4; ++i)
#pragma unroll
                for (int j = 0; j < 8; ++j)
                    acc[i][j] = fmaf(a[i], b[j], acc[i][j]);
        }
    }
    // write h
#pragma unroll
    for (int i = 0; i < 4; ++i) {
        float4 st0 = {acc[i][0], acc[i][1], acc[i][2], acc[i][3]};
        float4 st1 = {acc[i][4], acc[i][5], acc[i][6], acc[i][7]};
        float* hp = &h[(rowBase + (ty << 2) + i) * MO + (tx << 3)];
        *(float4*)hp = st0;
        *(float4*)(hp + 4) = st1;
    }
    // fused s1,s2,keys: per-row dot with a1/a2, reduce over the 16 tx lanes
    float4 a1lo = *(const float4*)&a1[tx << 3];
    float4 a1hi = *(const float4*)&a1[(tx << 3) + 4];
    float4 a2lo = *(const float4*)&a2[tx << 3];
    float4 a2hi = *(const float4*)&a2[(tx << 3) + 4];
    float a1v[8] = {a1lo.x, a1lo.y, a1lo.z, a1lo.w, a1hi.x, a1hi.y, a1hi.z, a1hi.w};
    float a2v[8] = {a2lo.x, a2lo.y, a2lo.z, a2lo.w, a2hi.x, a2hi.y, a2hi.z, a2hi.w};
#pragma unroll
    for (int r = 0; r < 4; ++r) {
        float p1 = 0.f, p2 = 0.f;
#pragma unroll
        for (int c = 0; c < 8; ++c) {
            p1 = fmaf(acc[r][c], a1v[c], p1);
            p2 = fmaf(acc[r][c], a2v[c], p2);
        }
#pragma unroll
        for (int off = 8; off; off >>= 1) {   // tx lanes are bits 0..3 of lane id
            p1 += __shfl_xor(p1, off, 64);
            p2 += __shfl_xor(p2, off, 64);
        }
        if (tx == 0) {
            int row = rowBase + (ty << 2) + r;
            s1[row] = p1;
            s2[row] = p2;
            keys[row] = sort_key(p1, row);
        }
    }
}

// ---------------- K2: partial rank counts via scalar key loads ----------------
__global__ __launch_bounds__(256) void k_rank(const u64* __restrict__ keys,
                                              int* __restrict__ rankPart) {
    const int t = threadIdx.x;
    const int i = blockIdx.x * 256 + t;
    const int jbase = blockIdx.y * (NR / 8);
    const u64 ki = keys[i];
    int cnt = 0;
#pragma unroll 8
    for (int jj = 0; jj < NR / 8; ++jj)
        cnt += (keys[jbase + jj] < ki) ? 1 : 0;
    rankPart[blockIdx.y * NR + i] = cnt;
}

// ---------------- K3: sum partials, scatter into sorted order ----------------
__global__ __launch_bounds__(256) void k_scatter(const float* __restrict__ s1,
                                                 const int* __restrict__ rankPart,
                                                 float* __restrict__ s1s,
                                                 int* __restrict__ perm) {
    int i = blockIdx.x * 256 + threadIdx.x;
    int r = 0;
#pragma unroll
    for (int p = 0; p < 8; ++p) r += rankPart[p * NR + i];
    s1s[r] = s1[i];
    perm[r] = i;
}

// ---------------- K4: kidx[i] = lower_bound(s1s, -s2[i]) ----------------
__global__ __launch_bounds__(256) void k_kidx(const float* __restrict__ s1s,
                                              const float* __restrict__ s2,
                                              int* __restrict__ kidx) {
    int i = blockIdx.x * 256 + threadIdx.x;
    float tv = -s2[i];
    int lo = 0, hi = NR;
    while (lo < hi) {
        int mid = (lo + hi) >> 1;
        if (s1s[mid] < tv) lo = mid + 1; else hi = mid;
    }
    kidx[i] = lo;
}

// ---------------- K5: per-chunk partial sums of sorted h, s1*h ----------------
__global__ __launch_bounds__(128) void k_psum(const float* __restrict__ h,
                                              const int* __restrict__ perm,
                                              const float* __restrict__ s1s,
                                              float* __restrict__ psumH,
                                              float* __restrict__ psumSH) {
    __shared__ int pi[CH];
    __shared__ float ss[CH];
    const int c = threadIdx.x, q = blockIdx.x;
    if (c < CH) { pi[c] = perm[q * CH + c]; ss[c] = s1s[q * CH + c]; }
    __syncthreads();
    float sh = 0.f, sv = 0.f;
#pragma unroll 4
    for (int m = 0; m < CH; ++m) {
        float v = h[pi[m] * MO + c];
        sh += v;
        sv = fmaf(ss[m], v, sv);
    }
    psumH[q * MO + c] = sh;
    psumSH[q * MO + c] = sv;
}

// ---------------- K6: super sums (16 chunks each) ----------------
__global__ __launch_bounds__(128) void k_ssum(const float* __restrict__ psumH,
                                              const float* __restrict__ psumSH,
                                              float* __restrict__ ssumH,
                                              float* __restrict__ ssumS) {
    const int c = threadIdx.x, s = blockIdx.x;
    float fh = 0.f, fs = 0.f;
#pragma unroll 4
    for (int k = 0; k < SUP; ++k) {
        fh += psumH[(s * SUP + k) * MO + c];
        fs += psumSH[(s * SUP + k) * MO + c];
    }
    ssumH[s * MO + c] = fh;
    ssumS[s * MO + c] = fs;
}

// ---------------- K7: exclusive suffix over chunks (chunkSuf[q] = sum over q'>q) ----------------
__global__ __launch_bounds__(128) void k_ssuf(const float* __restrict__ psumH,
                                              const float* __restrict__ psumSH,
                                              const float* __restrict__ ssumH,
                                              const float* __restrict__ ssumS,
                                              float* __restrict__ cSufH,
                                              float* __restrict__ cSufS,
                                              float* __restrict__ SH,
                                              float* __restrict__ SSH) {
    const int c = threadIdx.x, s = blockIdx.x;
    float rh = 0.f, rs = 0.f;
    for (int s2 = s + 1; s2 < NS; ++s2) {
        rh += ssumH[s2 * MO + c];
        rs += ssumS[s2 * MO + c];
    }
    for (int k = SUP - 1; k >= 0; --k) {
        int q = s * SUP + k;
        cSufH[q * MO + c] = rh;
        cSufS[q * MO + c] = rs;
        rh += psumH[q * MO + c];
        rs += psumSH[q * MO + c];
    }
    if (s == 0) { SH[(size_t)NR * MO + c] = 0.f; SSH[(size_t)NR * MO + c] = 0.f; }
}

// ---------------- K8: full suffix arrays SH[k], SSH[k] ----------------
__global__ __launch_bounds__(128) void k_suffix(const float* __restrict__ h,
                                                const int* __restrict__ perm,
                                                const float* __restrict__ s1s,
                                                const float* __restrict__ cSufH,
                                                const float* __restrict__ cSufS,
                                                float* __restrict__ SH,
                                                float* __restrict__ SSH) {
    __shared__ int pi[CH];
    __shared__ float ss[CH];
    const int c = threadIdx.x, q = blockIdx.x;
    if (c < CH) { pi[c] = perm[q * CH + c]; ss[c] = s1s[q * CH + c]; }
    __syncthreads();
    float runH = cSufH[q * MO + c], runS = cSufS[q * MO + c];
#pragma unroll 4
    for (int m = CH - 1; m >= 0; --m) {
        int gm = q * CH + m;
        float v = h[pi[m] * MO + c];
        runH += v;
        runS = fmaf(ss[m], v, runS);
        SH[(size_t)gm * MO + c] = runH;
        SSH[(size_t)gm * MO + c] = runS;
    }
}

// ---------------- K9: out[i][c] ----------------
__global__ __launch_bounds__(256) void k_final(const float* __restrict__ SH,
                                               const float* __restrict__ SSH,
                                               const float* __restrict__ s2,
                                               const int* __restrict__ kidx,
                                               float* __restrict__ out) {
    int idx = blockIdx.x * 256 + threadIdx.x;
    int i = idx >> 7, c = idx & 127;
    float s2v = s2[i];
    int k = kidx[i];
    float th = SH[c], tsh = SSH[c];
    float sh = SH[(size_t)k * MO + c], sshv = SSH[(size_t)k * MO + c];
    out[idx] = ALPHA * fmaf(s2v, th, tsh) + (1.f - ALPHA) * fmaf(s2v, sh, sshv);
}

extern "C" void kernel_launch(void* const* d_in, const int* in_sizes, int n_in,
                              void* d_out, int out_size, void* d_ws, size_t ws_size,
                              hipStream_t stream) {
    const float* x  = (const float*)d_in[0];
    const float* w  = (const float*)d_in[1];
    const float* a1 = (const float*)d_in[2];
    const float* a2 = (const float*)d_in[3];
    float* out = (float*)d_out;

    float* ws     = (float*)d_ws;
    float* h      = ws;                               // NR*MO
    float* SH     = h + (size_t)NR * MO;              // (NR+1)*MO
    float* SSH    = SH + (size_t)(NR + 1) * MO;       // (NR+1)*MO
    float* s1     = SSH + (size_t)(NR + 1) * MO;      // NR
    float* s2     = s1 + NR;                          // NR
    float* s1s    = s2 + NR;                          // NR
    u64*   keys   = (u64*)(s1s + NR);                 // NR u64 (= 2*NR floats)
    int*   perm   = (int*)(keys + NR);                // NR
    int*   kidx   = perm + NR;                        // NR
    float* psumH  = (float*)(kidx + NR);              // NCH*MO
    float* psumSH = psumH + NCH * MO;                 // NCH*MO
    int*   rankPart = (int*)psumH;                    // 8*NR ints — aliases psum pair (dead by K5)
    float* ssumH  = psumSH + NCH * MO;                // NS*MO
    float* ssumS  = ssumH + NS * MO;                  // NS*MO
    float* cSufH  = ssumS + NS * MO;                  // NCH*MO
    float* cSufS  = cSufH + NCH * MO;                 // NCH*MO

    k_gemm_fused<<<NR / 64, 256, 0, stream>>>(x, w, a1, a2, h, s1, s2, keys);
    k_rank<<<dim3(NR / 256, 8), 256, 0, stream>>>(keys, rankPart);
    k_scatter<<<NR / 256, 256, 0, stream>>>(s1, rankPart, s1s, perm);
    k_kidx<<<NR / 256, 256, 0, stream>>>(s1s, s2, kidx);
    k_psum<<<NCH, 128, 0, stream>>>(h, perm, s1s, psumH, psumSH);
    k_ssum<<<NS, 128, 0, stream>>>(psumH, psumSH, ssumH, ssumS);
    k_ssuf<<<NS, 128, 0, stream>>>(psumH, psumSH, ssumH, ssumS, cSufH, cSufS, SH, SSH);
    k_suffix<<<NCH, 128, 0, stream>>>(h, perm, s1s, cSufH, cSufS, SH, SSH);
    k_final<<<(NR * MO) / 256, 256, 0, stream>>>(SH, SSH, s2, kidx, out);
}

// Round 3
// 84.093 us; speedup vs baseline: 1.6336x; 1.6336x over previous
//
#include <hip/hip_runtime.h>
#include <stdint.h>

#define NR 16384
#define KI 256
#define MO 128
#define ALPHA 0.01f
#define CH 32            // rows per chunk
#define NCH (NR / CH)    // 512 chunks
#define RB 8             // i-keys per thread in k_rank
#define JT 256           // j-keys staged in LDS per block
#define NJ (NR / JT)     // 64 j-chunks

typedef unsigned long long u64;

// sortable key: monotone float order, index tie-break (rank is a bijection)
static __device__ __forceinline__ u64 sort_key(float f, int j) {
    unsigned u = __float_as_uint(f);
    u ^= ((unsigned)((int)u >> 31)) | 0x80000000u;
    return (((u64)u) << 14) | (unsigned)(j & 0x3FFF);
}

// ---------------- K1: h = x@W^T (64x128 tile) + fused s1,s2,keys ----------------
__global__ __launch_bounds__(256) void k_gemm_fused(const float* __restrict__ x,
                                                    const float* __restrict__ w,
                                                    const float* __restrict__ a1,
                                                    const float* __restrict__ a2,
                                                    float* __restrict__ h,
                                                    float* __restrict__ s1,
                                                    float* __restrict__ s2,
                                                    u64* __restrict__ keys) {
    __shared__ float As[16][68];    // [k][row]
    __shared__ float Bs[16][132];   // [k][col]
    const int t = threadIdx.x;
    const int rowBase = blockIdx.x * 64;
    const int tx = t & 15;          // col group: cols tx*8..tx*8+7
    const int ty = t >> 4;          // row group: rows ty*4..ty*4+3
    const int ar = t >> 2, ak = (t & 3) << 2;
    const int br = t >> 1, bk = (t & 1) << 3;
    float acc[4][8] = {};
    for (int k0 = 0; k0 < KI; k0 += 16) {
        float4 av  = *(const float4*)&x[(rowBase + ar) * KI + k0 + ak];
        float4 bv0 = *(const float4*)&w[br * KI + k0 + bk];
        float4 bv1 = *(const float4*)&w[br * KI + k0 + bk + 4];
        __syncthreads();
        As[ak + 0][ar] = av.x; As[ak + 1][ar] = av.y;
        As[ak + 2][ar] = av.z; As[ak + 3][ar] = av.w;
        Bs[bk + 0][br] = bv0.x; Bs[bk + 1][br] = bv0.y;
        Bs[bk + 2][br] = bv0.z; Bs[bk + 3][br] = bv0.w;
        Bs[bk + 4][br] = bv1.x; Bs[bk + 5][br] = bv1.y;
        Bs[bk + 6][br] = bv1.z; Bs[bk + 7][br] = bv1.w;
        __syncthreads();
#pragma unroll
        for (int k = 0; k < 16; ++k) {
            float4 a4 = *(const float4*)&As[k][ty << 2];
            float4 b0 = *(const float4*)&Bs[k][tx << 3];
            float4 b1 = *(const float4*)&Bs[k][(tx << 3) + 4];
            float a[4] = {a4.x, a4.y, a4.z, a4.w};
            float b[8] = {b0.x, b0.y, b0.z, b0.w, b1.x, b1.y, b1.z, b1.w};
#pragma unroll
            for (int i = 0; i < 4; ++i)
#pragma unroll
                for (int j = 0; j < 8; ++j)
                    acc[i][j] = fmaf(a[i], b[j], acc[i][j]);
        }
    }
#pragma unroll
    for (int i = 0; i < 4; ++i) {
        float4 st0 = {acc[i][0], acc[i][1], acc[i][2], acc[i][3]};
        float4 st1 = {acc[i][4], acc[i][5], acc[i][6], acc[i][7]};
        float* hp = &h[(rowBase + (ty << 2) + i) * MO + (tx << 3)];
        *(float4*)hp = st0;
        *(float4*)(hp + 4) = st1;
    }
    float4 a1lo = *(const float4*)&a1[tx << 3];
    float4 a1hi = *(const float4*)&a1[(tx << 3) + 4];
    float4 a2lo = *(const float4*)&a2[tx << 3];
    float4 a2hi = *(const float4*)&a2[(tx << 3) + 4];
    float a1v[8] = {a1lo.x, a1lo.y, a1lo.z, a1lo.w, a1hi.x, a1hi.y, a1hi.z, a1hi.w};
    float a2v[8] = {a2lo.x, a2lo.y, a2lo.z, a2lo.w, a2hi.x, a2hi.y, a2hi.z, a2hi.w};
#pragma unroll
    for (int r = 0; r < 4; ++r) {
        float p1 = 0.f, p2 = 0.f;
#pragma unroll
        for (int c = 0; c < 8; ++c) {
            p1 = fmaf(acc[r][c], a1v[c], p1);
            p2 = fmaf(acc[r][c], a2v[c], p2);
        }
#pragma unroll
        for (int off = 8; off; off >>= 1) {
            p1 += __shfl_xor(p1, off, 64);
            p2 += __shfl_xor(p2, off, 64);
        }
        if (tx == 0) {
            int row = rowBase + (ty << 2) + r;
            s1[row] = p1;
            s2[row] = p2;
            keys[row] = sort_key(p1, row);
        }
    }
}

// ---------------- K2: rank partials — LDS-broadcast j-keys, 8 i-keys/thread in VGPRs ----------------
__global__ __launch_bounds__(256) void k_rank(const u64* __restrict__ keys,
                                              int* __restrict__ rankPart) {
    __shared__ u64 sk[JT];
    const int t = threadIdx.x;
    const int ibase = blockIdx.x * (256 * RB);
    const int jbase = blockIdx.y * JT;
    sk[t] = keys[jbase + t];
    u64 ki[RB];
#pragma unroll
    for (int k = 0; k < RB; ++k) ki[k] = keys[ibase + k * 256 + t];
    int cnt[RB] = {};
    __syncthreads();
#pragma unroll 4
    for (int jj = 0; jj < JT; ++jj) {
        u64 kj = sk[jj];                 // uniform addr -> LDS broadcast, conflict-free
#pragma unroll
        for (int k = 0; k < RB; ++k)
            cnt[k] += (kj < ki[k]) ? 1 : 0;
    }
#pragma unroll
    for (int k = 0; k < RB; ++k)
        rankPart[blockIdx.y * NR + ibase + k * 256 + t] = cnt[k];
}

// ---------------- K3: sum partials, scatter into sorted order ----------------
__global__ __launch_bounds__(256) void k_scatter(const float* __restrict__ s1,
                                                 const int* __restrict__ rankPart,
                                                 float* __restrict__ s1s,
                                                 int* __restrict__ perm) {
    int i = blockIdx.x * 256 + threadIdx.x;
    int r = 0;
#pragma unroll
    for (int p = 0; p < NJ; ++p) r += rankPart[p * NR + i];
    s1s[r] = s1[i];
    perm[r] = i;
}

// ---------------- K4: kidx[i] = lower_bound(s1s, -s2[i]) ----------------
__global__ __launch_bounds__(256) void k_kidx(const float* __restrict__ s1s,
                                              const float* __restrict__ s2,
                                              int* __restrict__ kidx) {
    int i = blockIdx.x * 256 + threadIdx.x;
    float tv = -s2[i];
    int lo = 0, hi = NR;
    while (lo < hi) {
        int mid = (lo + hi) >> 1;
        if (s1s[mid] < tv) lo = mid + 1; else hi = mid;
    }
    kidx[i] = lo;
}

// ---------------- K5: per-chunk partial sums of sorted h, s1*h ----------------
__global__ __launch_bounds__(128) void k_psum(const float* __restrict__ h,
                                              const int* __restrict__ perm,
                                              const float* __restrict__ s1s,
                                              float* __restrict__ psumH,
                                              float* __restrict__ psumSH) {
    __shared__ int pi[CH];
    __shared__ float ss[CH];
    const int c = threadIdx.x, q = blockIdx.x;
    if (c < CH) { pi[c] = perm[q * CH + c]; ss[c] = s1s[q * CH + c]; }
    __syncthreads();
    float sh = 0.f, sv = 0.f;
#pragma unroll 4
    for (int m = 0; m < CH; ++m) {
        float v = h[pi[m] * MO + c];
        sh += v;
        sv = fmaf(ss[m], v, sv);
    }
    psumH[q * MO + c] = sh;
    psumSH[q * MO + c] = sv;
}

// ---------------- K6: parallel exclusive suffix scan over 512 chunk sums (one block per column) ----------------
__global__ __launch_bounds__(512) void k_scan(const float* __restrict__ psumH,
                                              const float* __restrict__ psumSH,
                                              float* __restrict__ cSufH,
                                              float* __restrict__ cSufS,
                                              float* __restrict__ SH,
                                              float* __restrict__ SSH) {
    __shared__ float bufH[NCH], bufS[NCH];
    const int c = blockIdx.x, q = threadIdx.x;
    float vh = psumH[q * MO + c], vs = psumSH[q * MO + c];
    bufH[q] = vh; bufS[q] = vs;
    __syncthreads();
#pragma unroll
    for (int off = 1; off < NCH; off <<= 1) {
        float ah = 0.f, as = 0.f;
        if (q + off < NCH) { ah = bufH[q + off]; as = bufS[q + off]; }
        __syncthreads();
        bufH[q] += ah; bufS[q] += as;
        __syncthreads();
    }
    cSufH[q * MO + c] = bufH[q] - vh;   // exclusive suffix (chunks > q)
    cSufS[q * MO + c] = bufS[q] - vs;
    if (q == 0) { SH[(size_t)NR * MO + c] = 0.f; SSH[(size_t)NR * MO + c] = 0.f; }
}

// ---------------- K7: full suffix arrays SH[k], SSH[k] ----------------
__global__ __launch_bounds__(128) void k_suffix(const float* __restrict__ h,
                                                const int* __restrict__ perm,
                                                const float* __restrict__ s1s,
                                                const float* __restrict__ cSufH,
                                                const float* __restrict__ cSufS,
                                                float* __restrict__ SH,
                                                float* __restrict__ SSH) {
    __shared__ int pi[CH];
    __shared__ float ss[CH];
    const int c = threadIdx.x, q = blockIdx.x;
    if (c < CH) { pi[c] = perm[q * CH + c]; ss[c] = s1s[q * CH + c]; }
    __syncthreads();
    float runH = cSufH[q * MO + c], runS = cSufS[q * MO + c];
#pragma unroll 4
    for (int m = CH - 1; m >= 0; --m) {
        int gm = q * CH + m;
        float v = h[pi[m] * MO + c];
        runH += v;
        runS = fmaf(ss[m], v, runS);
        SH[(size_t)gm * MO + c] = runH;
        SSH[(size_t)gm * MO + c] = runS;
    }
}

// ---------------- K8: out[i][c] ----------------
__global__ __launch_bounds__(256) void k_final(const float* __restrict__ SH,
                                               const float* __restrict__ SSH,
                                               const float* __restrict__ s2,
                                               const int* __restrict__ kidx,
                                               float* __restrict__ out) {
    int idx = blockIdx.x * 256 + threadIdx.x;
    int i = idx >> 7, c = idx & 127;
    float s2v = s2[i];
    int k = kidx[i];
    float th = SH[c], tsh = SSH[c];     // suffix from 0 = totals
    float sh = SH[(size_t)k * MO + c], sshv = SSH[(size_t)k * MO + c];
    out[idx] = ALPHA * fmaf(s2v, th, tsh) + (1.f - ALPHA) * fmaf(s2v, sh, sshv);
}

extern "C" void kernel_launch(void* const* d_in, const int* in_sizes, int n_in,
                              void* d_out, int out_size, void* d_ws, size_t ws_size,
                              hipStream_t stream) {
    const float* x  = (const float*)d_in[0];
    const float* w  = (const float*)d_in[1];
    const float* a1 = (const float*)d_in[2];
    const float* a2 = (const float*)d_in[3];
    float* out = (float*)d_out;

    float* ws     = (float*)d_ws;
    float* h      = ws;                               // NR*MO
    float* SH     = h + (size_t)NR * MO;              // (NR+1)*MO
    float* SSH    = SH + (size_t)(NR + 1) * MO;       // (NR+1)*MO
    float* s1     = SSH + (size_t)(NR + 1) * MO;      // NR
    float* s2     = s1 + NR;                          // NR
    float* s1s    = s2 + NR;                          // NR
    u64*   keys   = (u64*)(s1s + NR);                 // NR u64
    int*   perm   = (int*)(keys + NR);                // NR
    int*   kidx   = perm + NR;                        // NR
    float* psumH  = (float*)(kidx + NR);              // NCH*MO
    float* psumSH = psumH + NCH * MO;                 // NCH*MO
    float* cSufH  = psumSH + NCH * MO;                // NCH*MO
    float* cSufS  = cSufH + NCH * MO;                 // NCH*MO
    // rankPart (NJ*NR ints = 4 MB) aliases SH: dead before k_scan/k_suffix write SH
    int*   rankPart = (int*)SH;

    k_gemm_fused<<<NR / 64, 256, 0, stream>>>(x, w, a1, a2, h, s1, s2, keys);
    k_rank<<<dim3(NR / (256 * RB), NJ), 256, 0, stream>>>(keys, rankPart);
    k_scatter<<<NR / 256, 256, 0, stream>>>(s1, rankPart, s1s, perm);
    k_kidx<<<NR / 256, 256, 0, stream>>>(s1s, s2, kidx);
    k_psum<<<NCH, 128, 0, stream>>>(h, perm, s1s, psumH, psumSH);
    k_scan<<<MO, NCH, 0, stream>>>(psumH, psumSH, cSufH, cSufS, SH, SSH);
    k_suffix<<<NCH, 128, 0, stream>>>(h, perm, s1s, cSufH, cSufS, SH, SSH);
    k_final<<<(NR * MO) / 256, 256, 0, stream>>>(SH, SSH, s2, kidx, out);
}